// Round 1
// baseline (152.837 us; speedup 1.0000x reference)
//
#include <hip/hip_runtime.h>

// ---------------------------------------------------------------------------
// WindowAttention (trainingTag==2 fast path, tag==1 also supported):
//   q* = qm*scale (tag2) or q*scale (tag1)
//   attn   = softmax(q* @ k^T  + bias);  x_ivif = attn   @ v
//   attn_m = softmax(q* @ km^T + bias);  x_mfif = attn_m @ vm
// bias = MLP(rel_pos_log) precomputed by kernel 1 into d_ws in MFMA
// C-fragment order.
// B_=2048, N=64, H=6, hd=32, dim=192, C3=576.
// ---------------------------------------------------------------------------

typedef float  f32x4  __attribute__((ext_vector_type(4)));
typedef short  bf16x8 __attribute__((ext_vector_type(8)));   // 8 bf16 (4 VGPRs)
typedef unsigned short u16x8 __attribute__((ext_vector_type(8)));
typedef unsigned short u16x4 __attribute__((ext_vector_type(4)));

__device__ __forceinline__ unsigned short f2bf(float f) {
  unsigned int u = __builtin_bit_cast(unsigned int, f);
  unsigned int r = (u + 0x7FFFu + ((u >> 16) & 1u)) >> 16;   // RNE
  return (unsigned short)r;
}

// ---------------- kernel 1: bias MLP -> fragment-ordered workspace ----------
// ws layout: bias_ws[((h*16 + tile)*64 + lane)*4 + reg], tile = mt*4 + nt,
// value = bias[h][n][m], n = nt*16 + (lane&15), m = mt*16 + (lane>>4)*4 + reg.
__global__ void bias_mlp_kernel(const float* __restrict__ W1,
                                const float* __restrict__ b1,
                                const float* __restrict__ W2,
                                const float* __restrict__ b2,
                                float* __restrict__ bias_ws) {
  int idx  = blockIdx.x * 256 + threadIdx.x;   // 24576 threads total
  int reg  = idx & 3;
  int lane = (idx >> 2) & 63;
  int tile = (idx >> 8) & 15;
  int h    = idx >> 12;
  int mt = tile >> 2, nt = tile & 3;
  int n = nt * 16 + (lane & 15);
  int m = mt * 16 + (lane >> 4) * 4 + reg;
  float dr = (float)((n >> 3) - (m >> 3));
  float dc = (float)((n & 7) - (m & 7));
  float fr = copysignf(log1pf(fabsf(dr)), dr);
  float fc = copysignf(log1pf(fabsf(dc)), dc);
  float acc = b2[h];
  for (int jj = 0; jj < 256; ++jj) {
    float hid = fmaf(fr, W1[jj], fmaf(fc, W1[256 + jj], b1[jj]));
    hid = fmaxf(hid, 0.0f);
    acc = fmaf(hid, W2[jj * 6 + h], acc);
  }
  bias_ws[idx] = acc;
}

// ---------------- kernel 2: fused dual-stream window attention --------------
__global__ __launch_bounds__(256, 4)
void wattn_kernel(const float* __restrict__ qkv,
                  const float* __restrict__ mfif,
                  const float* __restrict__ bias_ws,
                  const int*   __restrict__ tagp,
                  float* __restrict__ out) {
  const int bid  = blockIdx.x;
  const int h    = bid % 6;
  const int b    = bid / 6;
  const int tid  = threadIdx.x;
  const int lane = tid & 63;
  const int w    = tid >> 6;        // wave id = n-tile (nt)
  const int j    = lane & 15;
  const int g    = lane >> 4;

  // pitches chosen so all b128/b64 LDS ops sit at the bank floor (~2-way max)
  __shared__ unsigned short qm_s[64][40];
  __shared__ unsigned short k_s [64][40];
  __shared__ unsigned short km_s[64][40];
  __shared__ unsigned short vT_s[2][32][72];   // [stream][d][m], m-blocks XOR-swizzled
  __shared__ unsigned short P_s [64][72];      // wave-private row slices, no barrier

  const int tag = *tagp;
  const float* qsrc = (tag == 2) ? mfif : qkv;   // tag2: qm; tag1: q
  const size_t base = (size_t)b * 36864;
  const float scale = 0.17677669529663687f;      // 32^-0.5

  // ---- stage q*(scaled), k, km: natural [64][32] bf16 ----
  {
    const int n = tid >> 2, seg = tid & 3;
    const float* pq = qsrc + base + (size_t)n * 576 +       h * 32 + seg * 8;
    const float* pk = qkv  + base + (size_t)n * 576 + 192 + h * 32 + seg * 8;
    const float* pm = mfif + base + (size_t)n * 576 + 192 + h * 32 + seg * 8;
    f32x4 q0 = *(const f32x4*)pq;  f32x4 q1 = *(const f32x4*)(pq + 4);
    f32x4 k0 = *(const f32x4*)pk;  f32x4 k1 = *(const f32x4*)(pk + 4);
    f32x4 m0 = *(const f32x4*)pm;  f32x4 m1 = *(const f32x4*)(pm + 4);
    u16x8 oq, ok, om;
#pragma unroll
    for (int e = 0; e < 4; ++e) {
      oq[e] = f2bf(q0[e] * scale); oq[e + 4] = f2bf(q1[e] * scale);
      ok[e] = f2bf(k0[e]);         ok[e + 4] = f2bf(k1[e]);
      om[e] = f2bf(m0[e]);         om[e + 4] = f2bf(m1[e]);
    }
    *(u16x8*)&qm_s[n][seg * 8] = oq;
    *(u16x8*)&k_s [n][seg * 8] = ok;
    *(u16x8*)&km_s[n][seg * 8] = om;
  }
  // ---- stage v, vm transposed: vT[d][m], m-block ^ ((d>>3)&3)<<3 ----
  {
    const int d  = tid & 31;
    const int m0 = (tid >> 5) * 8;
    const int ms = m0 ^ (((d >> 3) & 3) << 3);
    const float* pv  = qkv  + base + 384 + h * 32 + d;
    const float* pvm = mfif + base + 384 + h * 32 + d;
    u16x8 ov, om;
#pragma unroll
    for (int e = 0; e < 8; ++e) {
      ov[e] = f2bf(pv [(size_t)(m0 + e) * 576]);
      om[e] = f2bf(pvm[(size_t)(m0 + e) * 576]);
    }
    *(u16x8*)&vT_s[0][d][ms] = ov;
    *(u16x8*)&vT_s[1][d][ms] = om;
  }
  __syncthreads();

  // ---- per-wave invariants: q B-fragment (rows n = 16w..16w+15), bias ----
  bf16x8 bq = *(const bf16x8*)&qm_s[16 * w + j][g * 8];
  f32x4 bias4[4];
#pragma unroll
  for (int mt = 0; mt < 4; ++mt)
    bias4[mt] = *(const f32x4*)&bias_ws[(((h * 16) + mt * 4 + w) * 64 + lane) * 4];

#pragma unroll
  for (int s = 0; s < 2; ++s) {
    const unsigned short (*Ks)[40] = (s == 0) ? k_s : km_s;

    // S^T tiles: D[m_local][n_local] = sum_d K[m][d] * q[n][d] + bias
    f32x4 acc[4];
#pragma unroll
    for (int mt = 0; mt < 4; ++mt) {
      bf16x8 ak = *(const bf16x8*)&Ks[mt * 16 + j][g * 8];
      acc[mt] = __builtin_amdgcn_mfma_f32_16x16x32_bf16(ak, bq, bias4[mt], 0, 0, 0);
    }

    // softmax over m for column n = 16w + j: 16 in-lane + xor16/xor32
    float mx = -3.0e38f;
#pragma unroll
    for (int mt = 0; mt < 4; ++mt)
#pragma unroll
      for (int r = 0; r < 4; ++r) mx = fmaxf(mx, acc[mt][r]);
    mx = fmaxf(mx, __shfl_xor(mx, 16));
    mx = fmaxf(mx, __shfl_xor(mx, 32));
    float p[16];
    float sum = 0.0f;
#pragma unroll
    for (int mt = 0; mt < 4; ++mt)
#pragma unroll
      for (int r = 0; r < 4; ++r) {
        float e = __expf(acc[mt][r] - mx);
        p[mt * 4 + r] = e;
        sum += e;
      }
    sum += __shfl_xor(sum, 16);
    sum += __shfl_xor(sum, 32);
    const float inv = 1.0f / sum;

    // P -> LDS (wave-private rows), packed 4 consecutive m per b64 store
#pragma unroll
    for (int mt = 0; mt < 4; ++mt) {
      u16x4 pw;
#pragma unroll
      for (int r = 0; r < 4; ++r) pw[r] = f2bf(p[mt * 4 + r] * inv);
      *(u16x4*)&P_s[16 * w + j][mt * 16 + g * 4] = pw;
    }

    // PV: x[n][d] = sum_m P[n][m] v[m][d]
    f32x4 xo[2] = {{0.f, 0.f, 0.f, 0.f}, {0.f, 0.f, 0.f, 0.f}};
#pragma unroll
    for (int kt = 0; kt < 2; ++kt) {
      bf16x8 ap = *(const bf16x8*)&P_s[16 * w + j][kt * 32 + g * 8];
#pragma unroll
      for (int dt = 0; dt < 2; ++dt) {
        const int d   = 16 * dt + j;
        const int mrd = (32 * kt + 8 * g) ^ (((d >> 3) & 3) << 3);
        bf16x8 bv = *(const bf16x8*)&vT_s[s][d][mrd];
        xo[dt] = __builtin_amdgcn_mfma_f32_16x16x32_bf16(ap, bv, xo[dt], 0, 0, 0);
      }
    }

    // store: out[b][n][h*32 + d], stream 1 offset = 2048*64*192
    float* ob = out + (size_t)s * 25165824 + (size_t)b * 12288 + h * 32;
#pragma unroll
    for (int dt = 0; dt < 2; ++dt)
#pragma unroll
      for (int r = 0; r < 4; ++r)
        ob[(16 * w + g * 4 + r) * 192 + dt * 16 + j] = xo[dt][r];
  }
}

extern "C" void kernel_launch(void* const* d_in, const int* in_sizes, int n_in,
                              void* d_out, int out_size, void* d_ws, size_t ws_size,
                              hipStream_t stream) {
  const float* qkv  = (const float*)d_in[0];
  const float* mfif = (const float*)d_in[1];
  const float* W1   = (const float*)d_in[2];
  const float* b1   = (const float*)d_in[3];
  const float* W2   = (const float*)d_in[4];
  const float* b2   = (const float*)d_in[5];
  const int*   tag  = (const int*)d_in[6];
  float* out     = (float*)d_out;
  float* bias_ws = (float*)d_ws;   // 24576 floats = 96 KiB

  hipLaunchKernelGGL(bias_mlp_kernel, dim3(96), dim3(256), 0, stream,
                     W1, b1, W2, b2, bias_ws);
  hipLaunchKernelGGL(wattn_kernel, dim3(12288), dim3(256), 0, stream,
                     qkv, mfif, bias_ws, tag, out);
}